// Round 6
// baseline (2466.391 us; speedup 1.0000x reference)
//
#include <hip/hip_runtime.h>

#define RNN_T 2048
#define RNN_B 64
#define RNN_H 256
#define KSTR 20   // h LDS stride per 16-float k-block (16 + 4 pad)

typedef float v2f __attribute__((ext_vector_type(2)));

// ---------------------------------------------------------------------------
// Kernel 1: xproj[b,t,:] = embed[x[b,t]] @ Wx + b_fc   (written into hs region)
// ---------------------------------------------------------------------------
__global__ __launch_bounds__(256)
void xproj_kernel(const int* __restrict__ x, const float* __restrict__ embed,
                  const float* __restrict__ Wfc, const float* __restrict__ bfc,
                  float* __restrict__ hsb) {
    __shared__ int ixs[64];
    __shared__ __align__(16) float A[64][260];
    const int tid = threadIdx.x;
    const long rb0 = (long)blockIdx.x * 64;

    if (tid < 64) ixs[tid] = x[rb0 + tid];
    __syncthreads();

    {   // stage 64 gathered embed rows: 4 threads per row, 16 float4 each
        const int r = tid >> 2, q = tid & 3;
        const float* erow = embed + (long)ixs[r] * RNN_H;
        #pragma unroll
        for (int i = 0; i < 16; ++i) {
            const int c = q * 64 + i * 4;
            *(float4*)&A[r][c] = *(const float4*)(erow + c);
        }
    }
    __syncthreads();

    const int tj = tid & 31, tr = tid >> 5;
    const int r0 = tr * 8, j0 = tj * 4, j1 = 128 + tj * 4;

    float acc[8][8];
    #pragma unroll
    for (int i = 0; i < 8; ++i)
        #pragma unroll
        for (int c = 0; c < 8; ++c) acc[i][c] = 0.f;

    for (int k4 = 0; k4 < 64; ++k4) {
        float4 a[8];
        #pragma unroll
        for (int i = 0; i < 8; ++i) a[i] = *(const float4*)&A[r0 + i][k4 * 4];
        #pragma unroll
        for (int kk = 0; kk < 4; ++kk) {
            const int k = k4 * 4 + kk;
            const float4 wa = *(const float4*)(Wfc + (long)k * RNN_H + j0);
            const float4 wb = *(const float4*)(Wfc + (long)k * RNN_H + j1);
            #pragma unroll
            for (int i = 0; i < 8; ++i) {
                const float av = reinterpret_cast<const float*>(&a[i])[kk];
                acc[i][0] = fmaf(av, wa.x, acc[i][0]);
                acc[i][1] = fmaf(av, wa.y, acc[i][1]);
                acc[i][2] = fmaf(av, wa.z, acc[i][2]);
                acc[i][3] = fmaf(av, wa.w, acc[i][3]);
                acc[i][4] = fmaf(av, wb.x, acc[i][4]);
                acc[i][5] = fmaf(av, wb.y, acc[i][5]);
                acc[i][6] = fmaf(av, wb.z, acc[i][6]);
                acc[i][7] = fmaf(av, wb.w, acc[i][7]);
            }
        }
    }

    const float4 ba = *(const float4*)(bfc + j0);
    const float4 bb = *(const float4*)(bfc + j1);
    #pragma unroll
    for (int i = 0; i < 8; ++i) {
        const long row = rb0 + r0 + i;
        float4 o1 = make_float4(acc[i][0] + ba.x, acc[i][1] + ba.y,
                                acc[i][2] + ba.z, acc[i][3] + ba.w);
        float4 o2 = make_float4(acc[i][4] + bb.x, acc[i][5] + bb.y,
                                acc[i][6] + bb.z, acc[i][7] + bb.w);
        *(float4*)(hsb + row * RNN_H + j0) = o1;
        *(float4*)(hsb + row * RNN_H + j1) = o2;
    }
}

// ---------------------------------------------------------------------------
// Kernel 2: persistent RNN scan. One WG per batch row, 1024 threads (16 waves
// = 4/SIMD). R5 lesson: the wall is LDS h-DELIVERY (each lane re-reads its
// whole k-segment). New layout: G=16 k-split, C=4 columns per lane:
//   wave w (0..15), row cg = l>>4 (0..3), kseg kg = l&15.
//   lane's columns: w*16 + cg*4 + {0..3}; lane's rows: kg*16 .. +15.
// Per-lane h-read: 16 floats (4x ds_read_b128) -> 4x less LDS delivery than
// R5. Weights 64 floats/lane (32 v2f, static indices). 16-way k-reduce via
// 4 shfl_xor rounds within the l&15 group (no extra barrier). h stored with
// stride-20 16-float blocks -> kg lanes land on disjoint/2-way banks.
// Writer lanes (l&15)<4 do tanh + h/hs writes (explicit select, rule #20).
// ---------------------------------------------------------------------------
__global__ __launch_bounds__(1024, 4)
void rnn_scan_kernel(const float* __restrict__ Wfc, const float* __restrict__ Wout,
                     const float* __restrict__ bout, float* __restrict__ out,
                     float* __restrict__ hsb) {
    __shared__ __align__(16) float hbuf[2][16 * KSTR];
    const int tid = threadIdx.x;
    const int b = blockIdx.x;
    const int w = tid >> 6, l = tid & 63;
    const int cg = l >> 4;               // column sub-group 0..3
    const int kg = l & 15;               // k-segment 0..15 (16 rows)
    const int c0 = w * 16 + cg * 4;      // first of 4 contiguous columns
    const int k0 = kg * 16;              // first of 16 rows

    // --- weights: wv[c][rp] = {Wh[k0+2rp][c0+c], Wh[k0+2rp+1][c0+c]}, rp=0..7
    const float* Wh = Wfc + RNN_H * RNN_H;
    v2f wv[4][8];
    #pragma unroll
    for (int rp = 0; rp < 8; ++rp) {
        const long kb = (long)(k0 + 2 * rp) * RNN_H;
        #pragma unroll
        for (int c = 0; c < 4; ++c) {
            v2f t;
            t.x = Wh[kb + c0 + c];
            t.y = Wh[kb + RNN_H + c0 + c];
            wv[c][rp] = t;
        }
    }
    #pragma unroll
    for (int rp = 0; rp < 8; ++rp)
        asm volatile("" : "+v"(wv[0][rp]), "+v"(wv[1][rp]), "+v"(wv[2][rp]), "+v"(wv[3][rp]));

    if (tid < 16 * KSTR) hbuf[0][tid] = 0.f;

    float* xpb = hsb + (long)b * RNN_T * RNN_H;
    const int q = l & 15;                // writer id; writers have q<4
    const bool wr = (q < 4);
    const int jcol = c0 + (q & 3);       // writer's column
    float xr = 0.f, xn = 0.f;
    if (wr) {
        xr = xpb[jcol];
        xn = xpb[RNN_H + jcol];
    }
    __syncthreads();

    int cur = 0;
    for (int t = 0; t < RNN_T; ++t) {
        float xf = 0.f;
        if (wr && t + 2 < RNN_T)                      // 2-deep prefetch
            xf = xpb[(long)(t + 2) * RNN_H + jcol];

        // h rows k0..k0+15, stored at kg*KSTR (4x b128, 2-way banks max)
        const float4* h4 = (const float4*)(hbuf[cur] + kg * KSTR);
        const float4 h0v = h4[0], h1v = h4[1], h2v = h4[2], h3v = h4[3];
        const v2f hp[8] = { {h0v.x, h0v.y}, {h0v.z, h0v.w},
                            {h1v.x, h1v.y}, {h1v.z, h1v.w},
                            {h2v.x, h2v.y}, {h2v.z, h2v.w},
                            {h3v.x, h3v.y}, {h3v.z, h3v.w} };

        v2f acc[4];
        #pragma unroll
        for (int c = 0; c < 4; ++c) acc[c] = (v2f){0.f, 0.f};
        #pragma unroll
        for (int rp = 0; rp < 8; ++rp) {
            #pragma unroll
            for (int c = 0; c < 4; ++c)
                acc[c] = __builtin_elementwise_fma(hp[rp], wv[c][rp], acc[c]);
        }

        float s0 = acc[0].x + acc[0].y;
        float s1 = acc[1].x + acc[1].y;
        float s2 = acc[2].x + acc[2].y;
        float s3 = acc[3].x + acc[3].y;
        // 16-way k-reduce within the l&15 group
        #pragma unroll
        for (int m = 1; m <= 8; m <<= 1) {
            s0 += __shfl_xor(s0, m);
            s1 += __shfl_xor(s1, m);
            s2 += __shfl_xor(s2, m);
            s3 += __shfl_xor(s3, m);
        }

        if (wr) {
            // explicit select (static reg indices only — rule #20)
            const float sv = (q == 0) ? s0 : (q == 1) ? s1 : (q == 2) ? s2 : s3;
            const float v = sv + xr;
            const float e = __expf(2.f * v);
            const float hn = 1.f - 2.f * __builtin_amdgcn_rcpf(e + 1.f);  // tanh
            hbuf[cur ^ 1][w * KSTR + cg * 4 + (q & 3)] = hn;  // (jcol>>4)=w
            xpb[(long)t * RNN_H + jcol] = hn;                 // hs output
            xr = xn;
            xn = xf;
        }
        __syncthreads();
        cur ^= 1;
    }

    // epilogue: out[b,:] = h_last @ W_out + b_out  (first 256 threads)
    if (tid < RNN_H) {
        const float* hl = hbuf[cur];
        float a0 = 0.f, a1 = 0.f, a2 = 0.f, a3 = 0.f;
        for (int k = 0; k < RNN_H; k += 4) {
            const int kb = (k >> 4) * KSTR + (k & 15);
            a0 = fmaf(hl[kb + 0], Wout[(long)(k + 0) * RNN_H + tid], a0);
            a1 = fmaf(hl[kb + 1], Wout[(long)(k + 1) * RNN_H + tid], a1);
            a2 = fmaf(hl[kb + 2], Wout[(long)(k + 2) * RNN_H + tid], a2);
            a3 = fmaf(hl[kb + 3], Wout[(long)(k + 3) * RNN_H + tid], a3);
        }
        out[(long)b * RNN_H + tid] = a0 + a1 + a2 + a3 + bout[tid];
    }
}

extern "C" void kernel_launch(void* const* d_in, const int* in_sizes, int n_in,
                              void* d_out, int out_size, void* d_ws, size_t ws_size,
                              hipStream_t stream) {
    const int*   x     = (const int*)d_in[0];
    const float* embed = (const float*)d_in[1];
    const float* Wfc   = (const float*)d_in[2];
    const float* bfc   = (const float*)d_in[3];
    const float* Wout  = (const float*)d_in[4];
    const float* bout  = (const float*)d_in[5];

    float* out = (float*)d_out;                 // [B, 256]
    float* hsb = out + RNN_B * RNN_H;           // [B, T, H] region

    xproj_kernel<<<(RNN_B * RNN_T) / 64, 256, 0, stream>>>(x, embed, Wfc, bfc, hsb);
    rnn_scan_kernel<<<RNN_B, 1024, 0, stream>>>(Wfc, Wout, bout, out, hsb);
}

// Round 7
// 1464.147 us; speedup vs baseline: 1.6845x; 1.6845x over previous
//
#include <hip/hip_runtime.h>

#define RNN_T 2048
#define RNN_B 64
#define RNN_H 256
#define KBLK 36   // padded stride per 32-float k-block: banks 4*kg apart

typedef float v2f __attribute__((ext_vector_type(2)));

// ---------------------------------------------------------------------------
// Kernel 1: xproj[b,t,:] = embed[x[b,t]] @ Wx + b_fc   (written into hs region)
// ---------------------------------------------------------------------------
__global__ __launch_bounds__(256)
void xproj_kernel(const int* __restrict__ x, const float* __restrict__ embed,
                  const float* __restrict__ Wfc, const float* __restrict__ bfc,
                  float* __restrict__ hsb) {
    __shared__ int ixs[64];
    __shared__ __align__(16) float A[64][260];
    const int tid = threadIdx.x;
    const long rb0 = (long)blockIdx.x * 64;

    if (tid < 64) ixs[tid] = x[rb0 + tid];
    __syncthreads();

    {
        const int r = tid >> 2, q = tid & 3;
        const float* erow = embed + (long)ixs[r] * RNN_H;
        #pragma unroll
        for (int i = 0; i < 16; ++i) {
            const int c = q * 64 + i * 4;
            *(float4*)&A[r][c] = *(const float4*)(erow + c);
        }
    }
    __syncthreads();

    const int tj = tid & 31, tr = tid >> 5;
    const int r0 = tr * 8, j0 = tj * 4, j1 = 128 + tj * 4;

    float acc[8][8];
    #pragma unroll
    for (int i = 0; i < 8; ++i)
        #pragma unroll
        for (int c = 0; c < 8; ++c) acc[i][c] = 0.f;

    for (int k4 = 0; k4 < 64; ++k4) {
        float4 a[8];
        #pragma unroll
        for (int i = 0; i < 8; ++i) a[i] = *(const float4*)&A[r0 + i][k4 * 4];
        #pragma unroll
        for (int kk = 0; kk < 4; ++kk) {
            const int k = k4 * 4 + kk;
            const float4 wa = *(const float4*)(Wfc + (long)k * RNN_H + j0);
            const float4 wb = *(const float4*)(Wfc + (long)k * RNN_H + j1);
            #pragma unroll
            for (int i = 0; i < 8; ++i) {
                const float av = reinterpret_cast<const float*>(&a[i])[kk];
                acc[i][0] = fmaf(av, wa.x, acc[i][0]);
                acc[i][1] = fmaf(av, wa.y, acc[i][1]);
                acc[i][2] = fmaf(av, wa.z, acc[i][2]);
                acc[i][3] = fmaf(av, wa.w, acc[i][3]);
                acc[i][4] = fmaf(av, wb.x, acc[i][4]);
                acc[i][5] = fmaf(av, wb.y, acc[i][5]);
                acc[i][6] = fmaf(av, wb.z, acc[i][6]);
                acc[i][7] = fmaf(av, wb.w, acc[i][7]);
            }
        }
    }

    const float4 ba = *(const float4*)(bfc + j0);
    const float4 bb = *(const float4*)(bfc + j1);
    #pragma unroll
    for (int i = 0; i < 8; ++i) {
        const long row = rb0 + r0 + i;
        float4 o1 = make_float4(acc[i][0] + ba.x, acc[i][1] + ba.y,
                                acc[i][2] + ba.z, acc[i][3] + ba.w);
        float4 o2 = make_float4(acc[i][4] + bb.x, acc[i][5] + bb.y,
                                acc[i][6] + bb.z, acc[i][7] + bb.w);
        *(float4*)(hsb + row * RNN_H + j0) = o1;
        *(float4*)(hsb + row * RNN_H + j1) = o2;
    }
}

// ---------------------------------------------------------------------------
// 8-way sum within consecutive 8-lane groups, entirely on the VALU pipe
// (v_mov_dpp + v_add): quad_perm xor1, xor2, then row_half_mirror.
// R6 lesson: __shfl_xor is a DS-pipe op — 16 of them/step re-created the
// DS bottleneck. DPP keeps the reduce off the DS pipe.
// ---------------------------------------------------------------------------
__device__ __forceinline__ float red8_dpp(float x) {
    int v = __float_as_int(x);
    x += __int_as_float(__builtin_amdgcn_update_dpp(0, v, 0xB1, 0xf, 0xf, true));  // xor1
    v = __float_as_int(x);
    x += __int_as_float(__builtin_amdgcn_update_dpp(0, v, 0x4E, 0xf, 0xf, true));  // xor2
    v = __float_as_int(x);
    x += __int_as_float(__builtin_amdgcn_update_dpp(0, v, 0x141, 0xf, 0xf, true)); // half-mirror
    return x;
}

__device__ __forceinline__ v2f lo2(const float4 v) { return (v2f){v.x, v.y}; }
__device__ __forceinline__ v2f hi2(const float4 v) { return (v2f){v.z, v.w}; }

// ---------------------------------------------------------------------------
// Kernel 2: persistent RNN scan. One WG per batch row, 512 threads (8 waves,
// 2/SIMD). Lane (w, l): column group cg = w*8 + (l>>3) -> 4 cols c0=cg*4;
// k-segment kg = l&7 -> 32 rows k0=kg*32. DS-pipe model (fits R1..R6):
// DS wave-instrs/step = 256/C + shuffles; here C=4, 0 shuffles ->
// 64 ds_read_b128 (4x less than R1/R5), k-reduce on VALU via DPP.
// h stored in stride-36 32-float k-blocks: instruction i's 8 unique
// broadcast addresses land on banks 4*(kg+i)%32 — tile all 32 banks, 0 cfl.
// Weights 128 floats/lane, all-static indices (rule #20), asm-pinned.
// t-loop unrolled x2 (ping-pong LDS buffers); ONE barrier/step.
// ---------------------------------------------------------------------------
__global__ __launch_bounds__(512, 2)
void rnn_scan_kernel(const float* __restrict__ Wfc, const float* __restrict__ Wout,
                     const float* __restrict__ bout, float* __restrict__ out,
                     float* __restrict__ hsb) {
    __shared__ __align__(16) float hA[8 * KBLK];
    __shared__ __align__(16) float hB[8 * KBLK];
    const int tid = threadIdx.x;
    const int b = blockIdx.x;
    const int w = tid >> 6, l = tid & 63;
    const int cg = w * 8 + (l >> 3);     // column group 0..63
    const int kg = l & 7;                // k-segment 0..7
    const int c0 = cg * 4;               // 4 contiguous columns
    const int k0 = kg * 32;              // 32 rows

    // weights: wv[c][m] = {Wh[k0+2m][c0+c], Wh[k0+2m+1][c0+c]}, m=0..15
    const float* Wh = Wfc + RNN_H * RNN_H;
    v2f wv[4][16];
    #pragma unroll
    for (int m = 0; m < 16; ++m) {
        const long kb = (long)(k0 + 2 * m) * RNN_H;
        #pragma unroll
        for (int c = 0; c < 4; ++c) {
            v2f t;
            t.x = Wh[kb + c0 + c];
            t.y = Wh[kb + RNN_H + c0 + c];
            wv[c][m] = t;
        }
    }
    #pragma unroll
    for (int m = 0; m < 16; ++m)
        asm volatile("" : "+v"(wv[0][m]), "+v"(wv[1][m]), "+v"(wv[2][m]), "+v"(wv[3][m]));

    if (tid < 8 * KBLK) { hA[tid] = 0.f; }

    float* xpb = hsb + (long)b * RNN_T * RNN_H;
    const bool wr = (kg < 4);            // writer lanes own col c0+kg
    const int jcol = c0 + (kg & 3);
    const int widx = (jcol >> 5) * KBLK + (jcol & 31);   // LDS write slot
    float* xw = xpb + jcol;                               // hs write cursor
    const float* xpf = xpb + jcol + 2 * RNN_H;            // prefetch cursor
    const float* xend = xpb + (long)RNN_T * RNN_H;

    float xr = 0.f, xn = 0.f;
    if (wr) { xr = xpb[jcol]; xn = xpb[RNN_H + jcol]; }
    __syncthreads();

    const float4* rdA = (const float4*)(hA + kg * KBLK);
    const float4* rdB = (const float4*)(hB + kg * KBLK);

#define RNN_STEP(RD, WDST)                                                  \
    {                                                                       \
        float xf = 0.f;                                                     \
        if (wr && xpf < xend) xf = *xpf;                                    \
        xpf += RNN_H;                                                       \
        const float4 q0 = RD[0], q1 = RD[1], q2 = RD[2], q3 = RD[3];        \
        const float4 q4 = RD[4], q5 = RD[5], q6 = RD[6], q7 = RD[7];        \
        v2f a0 = {0.f,0.f}, a1 = {0.f,0.f}, a2 = {0.f,0.f}, a3 = {0.f,0.f}; \
        const v2f hp[16] = { lo2(q0), hi2(q0), lo2(q1), hi2(q1),            \
                             lo2(q2), hi2(q2), lo2(q3), hi2(q3),            \
                             lo2(q4), hi2(q4), lo2(q5), hi2(q5),            \
                             lo2(q6), hi2(q6), lo2(q7), hi2(q7) };          \
        _Pragma("unroll")                                                   \
        for (int m = 0; m < 16; ++m) {                                      \
            a0 = __builtin_elementwise_fma(hp[m], wv[0][m], a0);            \
            a1 = __builtin_elementwise_fma(hp[m], wv[1][m], a1);            \
            a2 = __builtin_elementwise_fma(hp[m], wv[2][m], a2);            \
            a3 = __builtin_elementwise_fma(hp[m], wv[3][m], a3);            \
        }                                                                   \
        const float r0 = red8_dpp(a0.x + a0.y);                             \
        const float r1 = red8_dpp(a1.x + a1.y);                             \
        const float r2 = red8_dpp(a2.x + a2.y);                             \
        const float r3 = red8_dpp(a3.x + a3.y);                             \
        if (wr) {                                                           \
            const float sv = (kg == 0) ? r0 : (kg == 1) ? r1                \
                           : (kg == 2) ? r2 : r3;                           \
            const float vsum = sv + xr;                                     \
            const float e = __expf(2.f * vsum);                             \
            const float hn = 1.f - 2.f * __builtin_amdgcn_rcpf(e + 1.f);    \
            WDST[widx] = hn;                                                \
            *xw = hn;                                                       \
            xr = xn; xn = xf;                                               \
        }                                                                   \
        xw += RNN_H;                                                        \
        __syncthreads();                                                    \
    }

    for (int t = 0; t < RNN_T; t += 2) {
        RNN_STEP(rdA, hB);     // even step: read hA, write hB
        RNN_STEP(rdB, hA);     // odd step:  read hB, write hA
    }
#undef RNN_STEP

    // epilogue: out[b,:] = h_last @ W_out + b_out  (h_last is in hA)
    if (tid < RNN_H) {
        float a0 = 0.f, a1 = 0.f, a2 = 0.f, a3 = 0.f;
        for (int k = 0; k < RNN_H; k += 4) {
            const int kb = (k >> 5) * KBLK + (k & 31);
            a0 = fmaf(hA[kb + 0], Wout[(long)(k + 0) * RNN_H + tid], a0);
            a1 = fmaf(hA[kb + 1], Wout[(long)(k + 1) * RNN_H + tid], a1);
            a2 = fmaf(hA[kb + 2], Wout[(long)(k + 2) * RNN_H + tid], a2);
            a3 = fmaf(hA[kb + 3], Wout[(long)(k + 3) * RNN_H + tid], a3);
        }
        out[(long)b * RNN_H + tid] = a0 + a1 + a2 + a3 + bout[tid];
    }
}

extern "C" void kernel_launch(void* const* d_in, const int* in_sizes, int n_in,
                              void* d_out, int out_size, void* d_ws, size_t ws_size,
                              hipStream_t stream) {
    const int*   x     = (const int*)d_in[0];
    const float* embed = (const float*)d_in[1];
    const float* Wfc   = (const float*)d_in[2];
    const float* bfc   = (const float*)d_in[3];
    const float* Wout  = (const float*)d_in[4];
    const float* bout  = (const float*)d_in[5];

    float* out = (float*)d_out;                 // [B, 256]
    float* hsb = out + RNN_B * RNN_H;           // [B, T, H] region

    xproj_kernel<<<(RNN_B * RNN_T) / 64, 256, 0, stream>>>(x, embed, Wfc, bfc, hsb);
    rnn_scan_kernel<<<RNN_B, 512, 0, stream>>>(Wfc, Wout, bout, out, hsb);
}

// Round 9
// 1328.662 us; speedup vs baseline: 1.8563x; 1.1020x over previous
//
#include <hip/hip_runtime.h>

#define RNN_T 2048
#define RNN_B 64
#define RNN_H 256
#define KSTR 20   // floats per 16-row k-block (16 + 4 pad): 16B-aligned

typedef float v2f __attribute__((ext_vector_type(2)));

// ---------------------------------------------------------------------------
// Kernel 1: xproj[b,t,:] = embed[x[b,t]] @ Wx + b_fc   (written into hs region)
// ---------------------------------------------------------------------------
__global__ __launch_bounds__(256)
void xproj_kernel(const int* __restrict__ x, const float* __restrict__ embed,
                  const float* __restrict__ Wfc, const float* __restrict__ bfc,
                  float* __restrict__ hsb) {
    __shared__ int ixs[64];
    __shared__ __align__(16) float A[64][260];
    const int tid = threadIdx.x;
    const long rb0 = (long)blockIdx.x * 64;

    if (tid < 64) ixs[tid] = x[rb0 + tid];
    __syncthreads();

    {
        const int r = tid >> 2, q = tid & 3;
        const float* erow = embed + (long)ixs[r] * RNN_H;
        #pragma unroll
        for (int i = 0; i < 16; ++i) {
            const int c = q * 64 + i * 4;
            *(float4*)&A[r][c] = *(const float4*)(erow + c);
        }
    }
    __syncthreads();

    const int tj = tid & 31, tr = tid >> 5;
    const int r0 = tr * 8, j0 = tj * 4, j1 = 128 + tj * 4;

    float acc[8][8];
    #pragma unroll
    for (int i = 0; i < 8; ++i)
        #pragma unroll
        for (int c = 0; c < 8; ++c) acc[i][c] = 0.f;

    for (int k4 = 0; k4 < 64; ++k4) {
        float4 a[8];
        #pragma unroll
        for (int i = 0; i < 8; ++i) a[i] = *(const float4*)&A[r0 + i][k4 * 4];
        #pragma unroll
        for (int kk = 0; kk < 4; ++kk) {
            const int k = k4 * 4 + kk;
            const float4 wa = *(const float4*)(Wfc + (long)k * RNN_H + j0);
            const float4 wb = *(const float4*)(Wfc + (long)k * RNN_H + j1);
            #pragma unroll
            for (int i = 0; i < 8; ++i) {
                const float av = reinterpret_cast<const float*>(&a[i])[kk];
                acc[i][0] = fmaf(av, wa.x, acc[i][0]);
                acc[i][1] = fmaf(av, wa.y, acc[i][1]);
                acc[i][2] = fmaf(av, wa.z, acc[i][2]);
                acc[i][3] = fmaf(av, wa.w, acc[i][3]);
                acc[i][4] = fmaf(av, wb.x, acc[i][4]);
                acc[i][5] = fmaf(av, wb.y, acc[i][5]);
                acc[i][6] = fmaf(av, wb.z, acc[i][6]);
                acc[i][7] = fmaf(av, wb.w, acc[i][7]);
            }
        }
    }

    const float4 ba = *(const float4*)(bfc + j0);
    const float4 bb = *(const float4*)(bfc + j1);
    #pragma unroll
    for (int i = 0; i < 8; ++i) {
        const long row = rb0 + r0 + i;
        float4 o1 = make_float4(acc[i][0] + ba.x, acc[i][1] + ba.y,
                                acc[i][2] + ba.z, acc[i][3] + ba.w);
        float4 o2 = make_float4(acc[i][4] + bb.x, acc[i][5] + bb.y,
                                acc[i][6] + bb.z, acc[i][7] + bb.w);
        *(float4*)(hsb + row * RNN_H + j0) = o1;
        *(float4*)(hsb + row * RNN_H + j1) = o2;
    }
}

// DPP hop on the VALU pipe. Lane-exchange facts (R8 post-mortem):
//   0xB1 quad_perm[1,0,3,2] = xor1     0x4E quad_perm[2,3,0,1] = xor2
//   0x1B quad_perm[3,2,1,0] = xor3     0x141 ROW_HALF_MIRROR   = xor7
//   0x128 ROW_ROR:8 (16-lane row)      = xor8
//   true xor4 = 0x1B then 0x141  ((i^3)^7 = i^4)
#define DPP_HOP(val, CTRL)                                                  \
    __int_as_float(__builtin_amdgcn_update_dpp(                             \
        0, __float_as_int(val), CTRL, 0xf, 0xf, true))

__device__ __forceinline__ v2f lo2(const float4 v) { return (v2f){v.x, v.y}; }
__device__ __forceinline__ v2f hi2(const float4 v) { return (v2f){v.z, v.w}; }

// ---------------------------------------------------------------------------
// Kernel 2: persistent RNN scan. One WG per batch row, 512 threads (8 waves,
// 2/SIMD). Lane (w,l): col group cg = w*4 + (l>>4) -> 8 cols c0 = cg*8;
// k-sub s = l&15 -> 16 rows k0 = s*16.
// DS: 4 ds_read_b128/lane (16 h floats) -> 32 wave-instrs/step/CU.
// 16-way k-reduce FUSED with 8->1 column merge (all VALU-pipe DPP):
//   stage1 xor1 mux bit0 (0xB1), stage2 xor2 mux bit1 (0x4E),
//   stage3 xor8 mux bit3 (ROW_ROR:8 0x128),
//   stage4 xor4 pure-add via 2-hop (0x1B then 0x141).
// Lane s ends with the FULL sum of column c0 + ((s&3)|((s&8)?4:0));
// writers are the (s&4)==0 lanes (bijective onto the 8 columns).
// Weights 128 floats/lane (static idx, rule #20), asm-pinned once.
// Ping-pong h buffers; ONE barrier/step.
// ---------------------------------------------------------------------------
__global__ __launch_bounds__(512, 2)
void rnn_scan_kernel(const float* __restrict__ Wfc, const float* __restrict__ Wout,
                     const float* __restrict__ bout, float* __restrict__ out,
                     float* __restrict__ hsb) {
    __shared__ __align__(16) float hA[16 * KSTR];
    __shared__ __align__(16) float hB[16 * KSTR];
    const int tid = threadIdx.x;
    const int b = blockIdx.x;
    const int w = tid >> 6, l = tid & 63;
    const int cg = w * 4 + (l >> 4);     // column group 0..31
    const int s  = l & 15;               // k-sub group 0..15
    const int c0 = cg * 8;               // 8 columns
    const int k0 = s * 16;               // 16 rows

    // weights: wv[c][m] = {Wh[k0+2m][c0+c], Wh[k0+2m+1][c0+c]}, c<8, m<8
    const float* Wh = Wfc + RNN_H * RNN_H;
    v2f wv[8][8];
    #pragma unroll
    for (int m = 0; m < 8; ++m) {
        const long kb = (long)(k0 + 2 * m) * RNN_H;
        #pragma unroll
        for (int c = 0; c < 8; ++c) {
            v2f t;
            t.x = Wh[kb + c0 + c];
            t.y = Wh[kb + RNN_H + c0 + c];
            wv[c][m] = t;
        }
    }
    #pragma unroll
    for (int m = 0; m < 8; ++m)
        asm volatile("" : "+v"(wv[0][m]), "+v"(wv[1][m]), "+v"(wv[2][m]), "+v"(wv[3][m]),
                          "+v"(wv[4][m]), "+v"(wv[5][m]), "+v"(wv[6][m]), "+v"(wv[7][m]));

    if (tid < 16 * KSTR) hA[tid] = 0.f;

    float* xpb = hsb + (long)b * RNN_T * RNN_H;
    const bool wr = ((s & 4) == 0);                      // 8 writers / 16-group
    const int jcol = c0 + ((s & 3) | ((s & 8) ? 4 : 0)); // lane's final column
    const int widx = (jcol >> 4) * KSTR + (jcol & 15);   // LDS write slot
    float* xw = xpb + jcol;                               // hs write cursor
    const float* xpf = xpb + jcol + 2 * RNN_H;            // prefetch cursor
    const float* xend = xpb + (long)RNN_T * RNN_H;

    float xr = 0.f, xn = 0.f;
    if (wr) { xr = xpb[jcol]; xn = xpb[RNN_H + jcol]; }
    __syncthreads();

    const float4* rdA = (const float4*)(hA + s * KSTR);
    const float4* rdB = (const float4*)(hB + s * KSTR);
    const bool m1 = (l & 1), m2 = (l & 2), m8 = (l & 8);

#define RNN_STEP(RD, WDST)                                                  \
    {                                                                       \
        float xf = 0.f;                                                     \
        if (wr && xpf < xend) xf = *xpf;                                    \
        xpf += RNN_H;                                                       \
        const float4 q0 = RD[0], q1 = RD[1], q2 = RD[2], q3 = RD[3];        \
        const v2f hp[8] = { lo2(q0), hi2(q0), lo2(q1), hi2(q1),             \
                            lo2(q2), hi2(q2), lo2(q3), hi2(q3) };           \
        v2f a0={0,0},a1={0,0},a2={0,0},a3={0,0},                            \
            a4={0,0},a5={0,0},a6={0,0},a7={0,0};                            \
        _Pragma("unroll")                                                   \
        for (int m = 0; m < 8; ++m) {                                       \
            a0 = __builtin_elementwise_fma(hp[m], wv[0][m], a0);            \
            a1 = __builtin_elementwise_fma(hp[m], wv[1][m], a1);            \
            a2 = __builtin_elementwise_fma(hp[m], wv[2][m], a2);            \
            a3 = __builtin_elementwise_fma(hp[m], wv[3][m], a3);            \
            a4 = __builtin_elementwise_fma(hp[m], wv[4][m], a4);            \
            a5 = __builtin_elementwise_fma(hp[m], wv[5][m], a5);            \
            a6 = __builtin_elementwise_fma(hp[m], wv[6][m], a6);            \
            a7 = __builtin_elementwise_fma(hp[m], wv[7][m], a7);            \
        }                                                                   \
        float s0=a0.x+a0.y, s1=a1.x+a1.y, s2=a2.x+a2.y, s3=a3.x+a3.y;       \
        float s4=a4.x+a4.y, s5=a5.x+a5.y, s6=a6.x+a6.y, s7=a7.x+a7.y;       \
        /* stage 1: xor1 (0xB1), 8 -> 4, mux bit0 */                        \
        float b0 = (m1 ? s1 : s0) + DPP_HOP(m1 ? s0 : s1, 0xB1);            \
        float b1 = (m1 ? s3 : s2) + DPP_HOP(m1 ? s2 : s3, 0xB1);            \
        float b2 = (m1 ? s5 : s4) + DPP_HOP(m1 ? s4 : s5, 0xB1);            \
        float b3 = (m1 ? s7 : s6) + DPP_HOP(m1 ? s6 : s7, 0xB1);            \
        /* stage 2: xor2 (0x4E), 4 -> 2, mux bit1 */                        \
        float c0v = (m2 ? b1 : b0) + DPP_HOP(m2 ? b0 : b1, 0x4E);           \
        float c1v = (m2 ? b3 : b2) + DPP_HOP(m2 ? b2 : b3, 0x4E);           \
        /* stage 3: xor8 (ROW_ROR:8 0x128), 2 -> 1, mux bit3 */             \
        float dv = (m8 ? c1v : c0v) + DPP_HOP(m8 ? c0v : c1v, 0x128);       \
        /* stage 4: xor4 pure add via 2-hop (0x1B then 0x141) */            \
        dv += DPP_HOP(DPP_HOP(dv, 0x1B), 0x141);                            \
        if (wr) {                                                           \
            const float vsum = dv + xr;                                     \
            const float e = __expf(2.f * vsum);                             \
            const float hn = 1.f - 2.f * __builtin_amdgcn_rcpf(e + 1.f);    \
            WDST[widx] = hn;                                                \
            *xw = hn;                                                       \
            xr = xn; xn = xf;                                               \
        }                                                                   \
        xw += RNN_H;                                                        \
        __syncthreads();                                                    \
    }

    for (int t = 0; t < RNN_T; t += 2) {
        RNN_STEP(rdA, hB);     // even step: read hA, write hB
        RNN_STEP(rdB, hA);     // odd step:  read hB, write hA
    }
#undef RNN_STEP

    // epilogue: out[b,:] = h_last @ W_out + b_out  (h_last is in hA)
    if (tid < RNN_H) {
        float a0 = 0.f, a1 = 0.f, a2 = 0.f, a3 = 0.f;
        for (int k = 0; k < RNN_H; k += 4) {
            const int kb = (k >> 4) * KSTR + (k & 15);
            a0 = fmaf(hA[kb + 0], Wout[(long)(k + 0) * RNN_H + tid], a0);
            a1 = fmaf(hA[kb + 1], Wout[(long)(k + 1) * RNN_H + tid], a1);
            a2 = fmaf(hA[kb + 2], Wout[(long)(k + 2) * RNN_H + tid], a2);
            a3 = fmaf(hA[kb + 3], Wout[(long)(k + 3) * RNN_H + tid], a3);
        }
        out[(long)b * RNN_H + tid] = a0 + a1 + a2 + a3 + bout[tid];
    }
}

extern "C" void kernel_launch(void* const* d_in, const int* in_sizes, int n_in,
                              void* d_out, int out_size, void* d_ws, size_t ws_size,
                              hipStream_t stream) {
    const int*   x     = (const int*)d_in[0];
    const float* embed = (const float*)d_in[1];
    const float* Wfc   = (const float*)d_in[2];
    const float* bfc   = (const float*)d_in[3];
    const float* Wout  = (const float*)d_in[4];
    const float* bout  = (const float*)d_in[5];

    float* out = (float*)d_out;                 // [B, 256]
    float* hsb = out + RNN_B * RNN_H;           // [B, T, H] region

    xproj_kernel<<<(RNN_B * RNN_T) / 64, 256, 0, stream>>>(x, embed, Wfc, bfc, hsb);
    rnn_scan_kernel<<<RNN_B, 512, 0, stream>>>(Wfc, Wout, bout, out, hsb);
}